// Round 6
// baseline (220.098 us; speedup 1.0000x reference)
//
#include <hip/hip_runtime.h>
#include <math.h>

#define Bn 8
#define Cn 112
#define Hn 64
#define Wn 64
#define On 112
#define Gn 14
#define PGC 378          // 3*G*K2
#define HW 4096          // 64*64
#define CKW 1008         // C*K2 (inner dim)
#define KP 1024          // padded K
#define NP 384           // padded N (oc) for pg GEMM
#define MFULL 32768      // full-batch pixel count
#define MHALF 16384      // half-batch pixel count

typedef __attribute__((ext_vector_type(8))) short bf16x8;
typedef __attribute__((ext_vector_type(4))) float f32x4;

__device__ __forceinline__ unsigned short f2bf(float f) {
    union { float f; unsigned int u; } v; v.f = f;
    unsigned int r = v.u + 0x7fffu + ((v.u >> 16) & 1u);
    return (unsigned short)(r >> 16);
}
__device__ __forceinline__ float bf2f(unsigned short u) {
    union { unsigned int u; float f; } v; v.u = ((unsigned int)u) << 16;
    return v.f;
}
__device__ __forceinline__ void gload_lds16(const void* g, void* l) {
    __builtin_amdgcn_global_load_lds(
        (const __attribute__((address_space(1))) unsigned int*)g,
        (__attribute__((address_space(3))) unsigned int*)l, 16, 0, 0);
}

// ---------------------------------------------------------------------------
// im2col -> A2 bf16 [count][1024], pixel range [px_base, px_base+count)
// ---------------------------------------------------------------------------
__global__ __launch_bounds__(256) void im2col_kernel(
    const float* __restrict__ x, unsigned short* __restrict__ A2, int px_base)
{
    int t = blockIdx.x * 256 + threadIdx.x;
    int pxl = t >> 7;
    int ck0 = (t & 127) << 3;
    int pxg = px_base + pxl;
    int b = pxg >> 12, hw = pxg & 4095;
    int h = hw >> 6, ww = hw & 63;
    const float* xb = x + (size_t)b * Cn * HW;

    unsigned short o[8];
    #pragma unroll
    for (int j = 0; j < 8; ++j) {
        int ck = ck0 + j;
        float v = 0.f;
        if (ck < CKW) {
            int c = ck / 9, k = ck - 9 * c;
            int yy = h + k / 3 - 1, xx = ww + (k % 3) - 1;
            if (yy >= 0 && yy < Hn && xx >= 0 && xx < Wn)
                v = xb[c * HW + yy * Wn + xx];
        }
        o[j] = f2bf(v);
    }
    *reinterpret_cast<uint4*>(&A2[(size_t)pxl * KP + ck0]) =
        *reinterpret_cast<const uint4*>(o);
}

// ---------------------------------------------------------------------------
// prep B2 bf16 [384][1024] from pg_weight
// ---------------------------------------------------------------------------
__global__ __launch_bounds__(256) void prep_b_kernel(
    const float* __restrict__ pgw, unsigned short* __restrict__ B2)
{
    int t = blockIdx.x * 256 + threadIdx.x;
    int oc = t >> 10, ck = t & 1023;
    float v = (oc < PGC && ck < CKW) ? pgw[(size_t)oc * CKW + ck] : 0.f;
    B2[t] = f2bf(v);
}

// ---------------------------------------------------------------------------
// prep WB bf16 [128][1024] from main weight, ck = g*72 + k*8 + cc
// (matches sample_kernel's output layout)
// ---------------------------------------------------------------------------
__global__ __launch_bounds__(256) void prep_wb_kernel(
    const float* __restrict__ w, unsigned short* __restrict__ WB)
{
    int t = blockIdx.x * 256 + threadIdx.x;   // 128*1024
    int oc = t >> 10, ck = t & 1023;
    float v = 0.f;
    if (oc < On && ck < CKW) {
        int g = ck / 72, r = ck % 72;
        int k = r >> 3, cc = r & 7;
        v = w[(size_t)oc * CKW + (g * 8 + cc) * 9 + k];
    }
    WB[t] = f2bf(v);
}

// ---------------------------------------------------------------------------
// pg GEMM  (m97 structure, validated rounds 2-5); px_base selects range
// ---------------------------------------------------------------------------
__global__ __launch_bounds__(256) void pg_gemm_kernel(
    const unsigned short* __restrict__ A2, const unsigned short* __restrict__ B2,
    const float* __restrict__ pgb, unsigned short* __restrict__ pgBF, int px_base)
{
    __shared__ __align__(16) unsigned short Asm[128 * 32];
    __shared__ __align__(16) unsigned short Bsm[128 * 32];

    const int tid  = threadIdx.x;
    const int lane = tid & 63;
    const int w    = tid >> 6;
    const int wr   = w >> 1, wc = w & 1;
    const int m0   = blockIdx.x * 128;
    const int n0   = blockIdx.y * 128;
    const int fr   = lane & 15, fq = lane >> 4;

    f32x4 acc[4][4] = {};

    const int ldr = lane >> 2;
    const int ldc = (lane & 3) * 8;

    for (int kt = 0; kt < 32; ++kt) {
        if (kt) __syncthreads();
        #pragma unroll
        for (int i = 0; i < 2; ++i) {
            int row = w * 32 + i * 16 + ldr;
            gload_lds16(&A2[(size_t)(m0 + row) * KP + kt * 32 + ldc],
                        &Asm[(w * 32 + i * 16) * 32]);
            gload_lds16(&B2[(size_t)(n0 + row) * KP + kt * 32 + ldc],
                        &Bsm[(w * 32 + i * 16) * 32]);
        }
        __syncthreads();

        bf16x8 a[4], b[4];
        #pragma unroll
        for (int mi = 0; mi < 4; ++mi)
            a[mi] = *reinterpret_cast<const bf16x8*>(
                &Asm[(wr * 64 + mi * 16 + fr) * 32 + fq * 8]);
        #pragma unroll
        for (int ni = 0; ni < 4; ++ni)
            b[ni] = *reinterpret_cast<const bf16x8*>(
                &Bsm[(wc * 64 + ni * 16 + fr) * 32 + fq * 8]);
        #pragma unroll
        for (int mi = 0; mi < 4; ++mi)
            #pragma unroll
            for (int ni = 0; ni < 4; ++ni)
                acc[mi][ni] = __builtin_amdgcn_mfma_f32_16x16x32_bf16(
                    a[mi], b[ni], acc[mi][ni], 0, 0, 0);
    }

    #pragma unroll
    for (int ni = 0; ni < 4; ++ni) {
        int oc = n0 + wc * 64 + ni * 16 + fr;
        if (oc >= PGC) continue;
        float bias = pgb[oc];
        #pragma unroll
        for (int mi = 0; mi < 4; ++mi) {
            int pxl = m0 + wr * 64 + mi * 16 + fq * 4;
            int pxg = px_base + pxl;
            int b = pxg >> 12, hw = pxg & 4095;
            ushort4 pk;
            pk.x = f2bf(acc[mi][ni][0] + bias);
            pk.y = f2bf(acc[mi][ni][1] + bias);
            pk.z = f2bf(acc[mi][ni][2] + bias);
            pk.w = f2bf(acc[mi][ni][3] + bias);
            *reinterpret_cast<ushort4*>(
                &pgBF[((size_t)(b * PGC + oc)) * HW + hw]) = pk;
        }
    }
}

// ---------------------------------------------------------------------------
// sample: one thread = (pixel, group, tap) x 8 channels. No LDS, no barriers;
// 32 gathers batched in registers; writes S bf16 [pxl][g*72+k*8+cc].
// ---------------------------------------------------------------------------
__global__ __launch_bounds__(256) void sample_kernel(
    const float* __restrict__ x, const unsigned short* __restrict__ pg,
    unsigned short* __restrict__ S, int px_base, int px_mask, int px_shift)
{
    int t = blockIdx.x * 256 + threadIdx.x;
    int pxl = t & px_mask;
    int gk  = t >> px_shift;          // 0..125
    int g = gk / 9, k = gk - 9 * g;
    int pxg = px_base + pxl;
    int b = pxg >> 12, hw = pxg & 4095;
    int y = hw >> 6, xc = hw & 63;

    // zero K-pad columns (one thread per row)
    if (gk == 0) {
        const uint4 z = {0, 0, 0, 0};
        *reinterpret_cast<uint4*>(&S[(size_t)pxl * KP + 1008]) = z;
        *reinterpret_cast<uint4*>(&S[(size_t)pxl * KP + 1016]) = z;
    }

    const unsigned short* pgb = pg + (size_t)b * PGC * HW + hw;
    float dy = bf2f(pgb[(size_t)(18 * g + 2 * k) * HW]);
    float dx = bf2f(pgb[(size_t)(18 * g + 2 * k + 1) * HW]);
    float mv = bf2f(pgb[(size_t)(252 + 9 * g + k) * HW]);
    float m  = 1.f / (1.f + __expf(-mv));

    const int ky = k / 3, kx = k % 3;
    float yf = (float)(y + ky - 1) + dy;
    float xf = (float)(xc + kx - 1) + dx;
    float y0 = floorf(yf), x0 = floorf(xf);
    float wy1 = yf - y0, wx1 = xf - x0;
    float wy0 = 1.f - wy1, wx0 = 1.f - wx1;
    int iy0 = (int)y0, ix0 = (int)x0;
    bool vy0 = (iy0 >= 0) && (iy0 < Hn);
    bool vy1 = (iy0 >= -1) && (iy0 < Hn - 1);
    bool vx0 = (ix0 >= 0) && (ix0 < Wn);
    bool vx1 = (ix0 >= -1) && (ix0 < Wn - 1);
    int cy0 = min(max(iy0, 0), Hn - 1), cy1 = min(max(iy0 + 1, 0), Hn - 1);
    int cx0 = min(max(ix0, 0), Wn - 1), cx1 = min(max(ix0 + 1, 0), Wn - 1);
    float w00 = (vy0 && vx0) ? wy0 * wx0 * m : 0.f;
    float w01 = (vy0 && vx1) ? wy0 * wx1 * m : 0.f;
    float w10 = (vy1 && vx0) ? wy1 * wx0 * m : 0.f;
    float w11 = (vy1 && vx1) ? wy1 * wx1 * m : 0.f;
    int i00 = cy0 * Wn + cx0, i01 = cy0 * Wn + cx1;
    int i10 = cy1 * Wn + cx0, i11 = cy1 * Wn + cx1;

    const float* xg = x + (size_t)(b * Cn + g * 8) * HW;

    // 32 independent gathers, all in flight before the reduction
    float v[8][4];
    #pragma unroll
    for (int c = 0; c < 8; ++c) {
        const float* img = xg + (size_t)c * HW;
        v[c][0] = img[i00]; v[c][1] = img[i01];
        v[c][2] = img[i10]; v[c][3] = img[i11];
    }
    unsigned int pk[4];
    #pragma unroll
    for (int c2 = 0; c2 < 4; ++c2) {
        float v0 = v[2*c2][0]*w00 + v[2*c2][1]*w01 + v[2*c2][2]*w10 + v[2*c2][3]*w11;
        float v1 = v[2*c2+1][0]*w00 + v[2*c2+1][1]*w01 + v[2*c2+1][2]*w10 + v[2*c2+1][3]*w11;
        pk[c2] = (unsigned int)f2bf(v0) | ((unsigned int)f2bf(v1) << 16);
    }
    *reinterpret_cast<uint4*>(&S[(size_t)pxl * KP + g * 72 + k * 8]) =
        *reinterpret_cast<const uint4*>(pk);
}

// ---------------------------------------------------------------------------
// main GEMM: out[b][oc][hw] = S[px][ck] * WB[oc][ck] + bias[oc]
// pg_gemm structure, N = 128 (single column tile), fp32 epilogue
// ---------------------------------------------------------------------------
__global__ __launch_bounds__(256) void main_gemm_kernel(
    const unsigned short* __restrict__ S, const unsigned short* __restrict__ WB,
    const float* __restrict__ bias, float* __restrict__ out, int px_base)
{
    __shared__ __align__(16) unsigned short Asm[128 * 32];
    __shared__ __align__(16) unsigned short Bsm[128 * 32];

    const int tid  = threadIdx.x;
    const int lane = tid & 63;
    const int w    = tid >> 6;
    const int wr   = w >> 1, wc = w & 1;
    const int m0   = blockIdx.x * 128;
    const int fr   = lane & 15, fq = lane >> 4;

    f32x4 acc[4][4] = {};

    const int ldr = lane >> 2;
    const int ldc = (lane & 3) * 8;

    for (int kt = 0; kt < 32; ++kt) {
        if (kt) __syncthreads();
        #pragma unroll
        for (int i = 0; i < 2; ++i) {
            int row = w * 32 + i * 16 + ldr;
            gload_lds16(&S[(size_t)(m0 + row) * KP + kt * 32 + ldc],
                        &Asm[(w * 32 + i * 16) * 32]);
            gload_lds16(&WB[(size_t)row * KP + kt * 32 + ldc],
                        &Bsm[(w * 32 + i * 16) * 32]);
        }
        __syncthreads();

        bf16x8 a[4], b[4];
        #pragma unroll
        for (int mi = 0; mi < 4; ++mi)
            a[mi] = *reinterpret_cast<const bf16x8*>(
                &Asm[(wr * 64 + mi * 16 + fr) * 32 + fq * 8]);
        #pragma unroll
        for (int ni = 0; ni < 4; ++ni)
            b[ni] = *reinterpret_cast<const bf16x8*>(
                &Bsm[(wc * 64 + ni * 16 + fr) * 32 + fq * 8]);
        #pragma unroll
        for (int mi = 0; mi < 4; ++mi)
            #pragma unroll
            for (int ni = 0; ni < 4; ++ni)
                acc[mi][ni] = __builtin_amdgcn_mfma_f32_16x16x32_bf16(
                    a[mi], b[ni], acc[mi][ni], 0, 0, 0);
    }

    #pragma unroll
    for (int ni = 0; ni < 4; ++ni) {
        int oc = wc * 64 + ni * 16 + fr;
        if (oc >= On) continue;
        float bv = bias[oc];
        #pragma unroll
        for (int mi = 0; mi < 4; ++mi) {
            int pxl = m0 + wr * 64 + mi * 16 + fq * 4;
            int pxg = px_base + pxl;
            int b = pxg >> 12, hw = pxg & 4095;
            float4 o;
            o.x = acc[mi][ni][0] + bv;
            o.y = acc[mi][ni][1] + bv;
            o.z = acc[mi][ni][2] + bv;
            o.w = acc[mi][ni][3] + bv;
            *reinterpret_cast<float4*>(
                &out[((size_t)(b * On + oc)) * HW + hw]) = o;
        }
    }
}

// ---------------------------------------------------------------------------
extern "C" void kernel_launch(void* const* d_in, const int* in_sizes, int n_in,
                              void* d_out, int out_size, void* d_ws, size_t ws_size,
                              hipStream_t stream) {
    const float* x    = (const float*)d_in[0];
    const float* pgw  = (const float*)d_in[1];
    const float* pgb  = (const float*)d_in[2];
    const float* w    = (const float*)d_in[3];
    const float* bias = (const float*)d_in[4];
    float* out = (float*)d_out;

    char* wsb = (char*)d_ws;
    unsigned short* pgBF = (unsigned short*)wsb;                 // 24.77 MB
    size_t off = (size_t)PGC * Bn * HW * 2;
    unsigned short* B2   = (unsigned short*)(wsb + off);         // 0.79 MB
    off += (size_t)NP * KP * 2;
    unsigned short* WB   = (unsigned short*)(wsb + off);         // 0.26 MB
    off += (size_t)128 * KP * 2;
    unsigned short* SA   = (unsigned short*)(wsb + off);         // A2/S shared region

    const bool full = ws_size >= off + (size_t)MFULL * KP * 2;   // 67.1 MB region
    const int cnt   = full ? MFULL : MHALF;
    const int shift = full ? 15 : 14;
    const int nh    = full ? 1 : 2;

    prep_b_kernel<<<NP * KP / 256, 256, 0, stream>>>(pgw, B2);
    prep_wb_kernel<<<128 * KP / 256, 256, 0, stream>>>(w, WB);

    // phase 1: pg = conv3x3(x) via im2col + MFMA GEMM
    for (int h = 0; h < nh; ++h) {
        im2col_kernel<<<cnt * 128 / 256, 256, 0, stream>>>(x, SA, h * cnt);
        dim3 gg(cnt / 128, NP / 128);
        pg_gemm_kernel<<<gg, 256, 0, stream>>>(SA, B2, pgb, pgBF, h * cnt);
    }

    // phase 2: deformable sampling -> S, then main GEMM -> out
    for (int h = 0; h < nh; ++h) {
        sample_kernel<<<(cnt / 256) * 126, 256, 0, stream>>>(
            x, pgBF, SA, h * cnt, cnt - 1, shift);
        main_gemm_kernel<<<dim3(cnt / 128, 1), 256, 0, stream>>>(
            SA, WB, bias, out, h * cnt);
    }
}

// Round 7
// 213.540 us; speedup vs baseline: 1.0307x; 1.0307x over previous
//
#include <hip/hip_runtime.h>
#include <math.h>

#define Bn 8
#define Cn 112
#define Hn 64
#define Wn 64
#define On 112
#define Gn 14
#define PGC 378          // 3*G*K2
#define HW 4096          // 64*64
#define CKW 1008         // C*K2
#define KP 1024          // padded K for main GEMM (sampled layout)
#define NP 384           // padded N (oc) for pg GEMM
#define KSH 1152         // shift-GEMM K = 9 taps * 128 padded channels
#define CP 128           // padded channel count
#define MFULL 32768
#define MHALF 16384
#define XROW 4356        // 66*66 rows per batch in XT
#define MPAD 34944       // 273*128 (tile-padded px'' domain; real = 8*4356=34848)
#define XGUARD 67        // guard rows before/after
#define XALLOC_ROWS (XGUARD + MPAD + XGUARD + 2)   // 35080

typedef __attribute__((ext_vector_type(8))) short bf16x8;
typedef __attribute__((ext_vector_type(4))) float f32x4;

__device__ __forceinline__ unsigned short f2bf(float f) {
    union { float f; unsigned int u; } v; v.f = f;
    unsigned int r = v.u + 0x7fffu + ((v.u >> 16) & 1u);
    return (unsigned short)(r >> 16);
}
__device__ __forceinline__ float bf2f(unsigned short u) {
    union { unsigned int u; float f; } v; v.u = ((unsigned int)u) << 16;
    return v.f;
}
__device__ __forceinline__ void gload_lds16(const void* g, void* l) {
    __builtin_amdgcn_global_load_lds(
        (const __attribute__((address_space(1))) unsigned int*)g,
        (__attribute__((address_space(3))) unsigned int*)l, 16, 0, 0);
}

// ---------------------------------------------------------------------------
// prep (merged): zero XT alloc | B2 shift-layout [384][1152] | WB [128][1024]
// ---------------------------------------------------------------------------
#define ZN (XALLOC_ROWS * CP / 8)        // uint4 count for XT zero = 561280
#define B2N (NP * KSH)                   // 442368
#define WBN (128 * KP)                   // 131072
__global__ __launch_bounds__(256) void prep_kernel(
    const float* __restrict__ pgw, const float* __restrict__ w,
    unsigned short* __restrict__ XTa, unsigned short* __restrict__ B2,
    unsigned short* __restrict__ WB)
{
    int t = blockIdx.x * 256 + threadIdx.x;
    if (t < ZN) {
        const uint4 z = {0, 0, 0, 0};
        reinterpret_cast<uint4*>(XTa)[t] = z;
        return;
    }
    t -= ZN;
    if (t < B2N) {
        int oc = t / KSH, ckk = t - oc * KSH;
        int k = ckk >> 7, c = ckk & 127;
        float v = (c < Cn && oc < PGC) ? pgw[(size_t)oc * CKW + c * 9 + k] : 0.f;
        B2[t] = f2bf(v);
        return;
    }
    t -= B2N;
    if (t < WBN) {
        int oc = t >> 10, ck = t & 1023;
        float v = 0.f;
        if (oc < On && ck < CKW) {
            int g = ck / 72, r = ck % 72;
            int k = r >> 3, cc = r & 7;
            v = w[(size_t)oc * CKW + (g * 8 + cc) * 9 + k];
        }
        WB[t] = f2bf(v);
    }
}

// ---------------------------------------------------------------------------
// xpose: x NCHW f32 -> XT bf16 rows [(b*66 + y+1)*66 + x+1][128]
// block = (y, b); LDS transpose; interior only (halo pre-zeroed by prep)
// ---------------------------------------------------------------------------
__global__ __launch_bounds__(256) void xpose_kernel(
    const float* __restrict__ x, unsigned short* __restrict__ XT)
{
    __shared__ unsigned short lds[64][136];   // 272B rows (16B-aligned)

    const int tid = threadIdx.x;
    const int y = blockIdx.x, b = blockIdx.y;
    const int xx = tid & 63, cw = tid >> 6;

    const float* xb = x + (size_t)b * Cn * HW + y * 64;
    #pragma unroll
    for (int p = 0; p < 28; ++p) {
        int c = p * 4 + cw;
        lds[xx][c] = f2bf(xb[(size_t)c * HW + xx]);
        if (p < 4) lds[xx][112 + p * 4 + cw] = 0;   // c-pad
    }
    __syncthreads();

    const int rx = tid >> 2, seg = tid & 3;
    size_t row = (size_t)(b * 66 + y + 1) * 66 + rx + 1;
    unsigned short* dst = XT + row * CP + seg * 32;
    const unsigned short* srcr = &lds[rx][seg * 32];
    #pragma unroll
    for (int j = 0; j < 4; ++j)
        *reinterpret_cast<uint4*>(dst + j * 8) =
            *reinterpret_cast<const uint4*>(srcr + j * 8);
}

// ---------------------------------------------------------------------------
// pg shift-GEMM: pg[oc][px] = sum_k sum_c W[oc][c,k] * XT[px + shift_k][c]
// 128x128 tile, 36 K-steps (9 taps x 4 c-chunks of 32), m97 structure
// ---------------------------------------------------------------------------
__global__ __launch_bounds__(256) void pg_shift_kernel(
    const unsigned short* __restrict__ XT, const unsigned short* __restrict__ B2,
    const float* __restrict__ pgb, unsigned short* __restrict__ pgBF)
{
    __shared__ __align__(16) unsigned short Asm[128 * 32];
    __shared__ __align__(16) unsigned short Bsm[128 * 32];

    const int tid  = threadIdx.x;
    const int lane = tid & 63;
    const int w    = tid >> 6;
    const int wr   = w >> 1, wc = w & 1;
    const int m0   = blockIdx.x * 128;
    const int n0   = blockIdx.y * 128;
    const int fr   = lane & 15, fq = lane >> 4;

    f32x4 acc[4][4] = {};

    const int ldr = lane >> 2;            // row within 16-row chunk
    const int ldcA = (lane & 3) * 8;      // ushort offset within 64B A-row
    const int ldcB = (lane & 3) * 8;

    for (int kt = 0; kt < 36; ++kt) {
        const int k = kt >> 2;
        const int shift = (k / 3 - 1) * 66 + (k % 3 - 1);
        const int c0 = (kt & 3) * 32;
        if (kt) __syncthreads();
        #pragma unroll
        for (int i = 0; i < 2; ++i) {
            int row = w * 32 + i * 16 + ldr;
            gload_lds16(&XT[(size_t)(m0 + row + shift) * CP + c0 + ldcA],
                        &Asm[(w * 32 + i * 16) * 32]);
            gload_lds16(&B2[(size_t)(n0 + row) * KSH + kt * 32 + ldcB],
                        &Bsm[(w * 32 + i * 16) * 32]);
        }
        __syncthreads();

        bf16x8 a[4], b[4];
        #pragma unroll
        for (int mi = 0; mi < 4; ++mi)
            a[mi] = *reinterpret_cast<const bf16x8*>(
                &Asm[(wr * 64 + mi * 16 + fr) * 32 + fq * 8]);
        #pragma unroll
        for (int ni = 0; ni < 4; ++ni)
            b[ni] = *reinterpret_cast<const bf16x8*>(
                &Bsm[(wc * 64 + ni * 16 + fr) * 32 + fq * 8]);
        #pragma unroll
        for (int mi = 0; mi < 4; ++mi)
            #pragma unroll
            for (int ni = 0; ni < 4; ++ni)
                acc[mi][ni] = __builtin_amdgcn_mfma_f32_16x16x32_bf16(
                    a[mi], b[ni], acc[mi][ni], 0, 0, 0);
    }

    #pragma unroll
    for (int ni = 0; ni < 4; ++ni) {
        int oc = n0 + wc * 64 + ni * 16 + fr;
        if (oc >= PGC) continue;
        float bias = pgb[oc];
        #pragma unroll
        for (int mi = 0; mi < 4; ++mi) {
            int pxq = m0 + wr * 64 + mi * 16 + fq * 4;
            #pragma unroll
            for (int r = 0; r < 4; ++r) {
                int pxd = pxq + r;
                if (pxd >= Bn * XROW) continue;
                int bb = pxd / XROW;
                int rem = pxd - bb * XROW;
                int yy = rem / 66 - 1;
                int xx = rem - (yy + 1) * 66 - 1;
                if ((unsigned)yy < 64u && (unsigned)xx < 64u)
                    pgBF[((size_t)(bb * PGC + oc)) * HW + yy * 64 + xx] =
                        f2bf(acc[mi][ni][r] + bias);
            }
        }
    }
}

// ---------------------------------------------------------------------------
// sample: thread = (pixel, group); 9 taps x 8 channels; 32-gather batches;
// writes 144B contiguous per thread into S [pxl][g*72 + k*8 + cc]
// ---------------------------------------------------------------------------
__global__ __launch_bounds__(256, 4) void sample_kernel(
    const float* __restrict__ x, const unsigned short* __restrict__ pg,
    unsigned short* __restrict__ S, int px_base)
{
    const int pxl = blockIdx.x * 256 + threadIdx.x;
    const int g   = blockIdx.y;
    const int pxg = px_base + pxl;
    const int b = pxg >> 12, hw = pxg & 4095;
    const int y = hw >> 6, xc = hw & 63;

    const unsigned short* pgb = pg + (size_t)b * PGC * HW + hw;
    const unsigned short* pgo = pgb + (size_t)(18 * g) * HW;
    const unsigned short* pgm = pgb + (size_t)(252 + 9 * g) * HW;

    // prefetch all 27 pg values (independent coalesced loads)
    float dyv[9], dxv[9], mvv[9];
    #pragma unroll
    for (int k = 0; k < 9; ++k) {
        dyv[k] = bf2f(pgo[(size_t)(2 * k) * HW]);
        dxv[k] = bf2f(pgo[(size_t)(2 * k + 1) * HW]);
        mvv[k] = bf2f(pgm[(size_t)k * HW]);
    }

    const float* xg = x + (size_t)(b * Cn + g * 8) * HW;
    unsigned short* so = &S[(size_t)pxl * KP + g * 72];

    #pragma unroll
    for (int k = 0; k < 9; ++k) {
        const int ky = k / 3, kx = k % 3;
        float m = 1.f / (1.f + __expf(-mvv[k]));

        float yf = (float)(y + ky - 1) + dyv[k];
        float xf = (float)(xc + kx - 1) + dxv[k];
        float y0 = floorf(yf), x0 = floorf(xf);
        float wy1 = yf - y0, wx1 = xf - x0;
        float wy0 = 1.f - wy1, wx0 = 1.f - wx1;
        int iy0 = (int)y0, ix0 = (int)x0;
        bool vy0 = (iy0 >= 0) && (iy0 < Hn);
        bool vy1 = (iy0 >= -1) && (iy0 < Hn - 1);
        bool vx0 = (ix0 >= 0) && (ix0 < Wn);
        bool vx1 = (ix0 >= -1) && (ix0 < Wn - 1);
        int cy0 = min(max(iy0, 0), Hn - 1), cy1 = min(max(iy0 + 1, 0), Hn - 1);
        int cx0 = min(max(ix0, 0), Wn - 1), cx1 = min(max(ix0 + 1, 0), Wn - 1);
        float w00 = (vy0 && vx0) ? wy0 * wx0 * m : 0.f;
        float w01 = (vy0 && vx1) ? wy0 * wx1 * m : 0.f;
        float w10 = (vy1 && vx0) ? wy1 * wx0 * m : 0.f;
        float w11 = (vy1 && vx1) ? wy1 * wx1 * m : 0.f;
        int i00 = cy0 * Wn + cx0, i01 = cy0 * Wn + cx1;
        int i10 = cy1 * Wn + cx0, i11 = cy1 * Wn + cx1;

        // 32 independent gathers in flight before the reduction
        float v[8][4];
        #pragma unroll
        for (int c = 0; c < 8; ++c) {
            const float* img = xg + (size_t)c * HW;
            v[c][0] = img[i00]; v[c][1] = img[i01];
            v[c][2] = img[i10]; v[c][3] = img[i11];
        }
        unsigned int pk[4];
        #pragma unroll
        for (int c2 = 0; c2 < 4; ++c2) {
            float v0 = v[2*c2][0]*w00 + v[2*c2][1]*w01 + v[2*c2][2]*w10 + v[2*c2][3]*w11;
            float v1 = v[2*c2+1][0]*w00 + v[2*c2+1][1]*w01 + v[2*c2+1][2]*w10 + v[2*c2+1][3]*w11;
            pk[c2] = (unsigned int)f2bf(v0) | ((unsigned int)f2bf(v1) << 16);
        }
        *reinterpret_cast<uint4*>(so + k * 8) =
            *reinterpret_cast<const uint4*>(pk);
    }

    if (g == Gn - 1) {   // zero K-pad columns 1008..1023
        const uint4 z = {0, 0, 0, 0};
        *reinterpret_cast<uint4*>(&S[(size_t)pxl * KP + 1008]) = z;
        *reinterpret_cast<uint4*>(&S[(size_t)pxl * KP + 1016]) = z;
    }
}

// ---------------------------------------------------------------------------
// main GEMM: out[b][oc][hw] = S[px][ck] * WB[oc][ck] + bias[oc]
// ---------------------------------------------------------------------------
__global__ __launch_bounds__(256) void main_gemm_kernel(
    const unsigned short* __restrict__ S, const unsigned short* __restrict__ WB,
    const float* __restrict__ bias, float* __restrict__ out, int px_base)
{
    __shared__ __align__(16) unsigned short Asm[128 * 32];
    __shared__ __align__(16) unsigned short Bsm[128 * 32];

    const int tid  = threadIdx.x;
    const int lane = tid & 63;
    const int w    = tid >> 6;
    const int wr   = w >> 1, wc = w & 1;
    const int m0   = blockIdx.x * 128;
    const int fr   = lane & 15, fq = lane >> 4;

    f32x4 acc[4][4] = {};

    const int ldr = lane >> 2;
    const int ldc = (lane & 3) * 8;

    for (int kt = 0; kt < 32; ++kt) {
        if (kt) __syncthreads();
        #pragma unroll
        for (int i = 0; i < 2; ++i) {
            int row = w * 32 + i * 16 + ldr;
            gload_lds16(&S[(size_t)(m0 + row) * KP + kt * 32 + ldc],
                        &Asm[(w * 32 + i * 16) * 32]);
            gload_lds16(&WB[(size_t)row * KP + kt * 32 + ldc],
                        &Bsm[(w * 32 + i * 16) * 32]);
        }
        __syncthreads();

        bf16x8 a[4], b[4];
        #pragma unroll
        for (int mi = 0; mi < 4; ++mi)
            a[mi] = *reinterpret_cast<const bf16x8*>(
                &Asm[(wr * 64 + mi * 16 + fr) * 32 + fq * 8]);
        #pragma unroll
        for (int ni = 0; ni < 4; ++ni)
            b[ni] = *reinterpret_cast<const bf16x8*>(
                &Bsm[(wc * 64 + ni * 16 + fr) * 32 + fq * 8]);
        #pragma unroll
        for (int mi = 0; mi < 4; ++mi)
            #pragma unroll
            for (int ni = 0; ni < 4; ++ni)
                acc[mi][ni] = __builtin_amdgcn_mfma_f32_16x16x32_bf16(
                    a[mi], b[ni], acc[mi][ni], 0, 0, 0);
    }

    #pragma unroll
    for (int ni = 0; ni < 4; ++ni) {
        int oc = wc * 64 + ni * 16 + fr;
        if (oc >= On) continue;
        float bv = bias[oc];
        #pragma unroll
        for (int mi = 0; mi < 4; ++mi) {
            int pxl = m0 + wr * 64 + mi * 16 + fq * 4;
            int pxg = px_base + pxl;
            int b = pxg >> 12, hw = pxg & 4095;
            float4 o;
            o.x = acc[mi][ni][0] + bv;
            o.y = acc[mi][ni][1] + bv;
            o.z = acc[mi][ni][2] + bv;
            o.w = acc[mi][ni][3] + bv;
            *reinterpret_cast<float4*>(
                &out[((size_t)(b * On + oc)) * HW + hw]) = o;
        }
    }
}

// ---------------------------------------------------------------------------
extern "C" void kernel_launch(void* const* d_in, const int* in_sizes, int n_in,
                              void* d_out, int out_size, void* d_ws, size_t ws_size,
                              hipStream_t stream) {
    const float* x    = (const float*)d_in[0];
    const float* pgw  = (const float*)d_in[1];
    const float* pgb  = (const float*)d_in[2];
    const float* w    = (const float*)d_in[3];
    const float* bias = (const float*)d_in[4];
    float* out = (float*)d_out;

    char* wsb = (char*)d_ws;
    unsigned short* pgBF = (unsigned short*)wsb;                 // 24.77 MB
    size_t off = (size_t)PGC * Bn * HW * 2;
    unsigned short* B2   = (unsigned short*)(wsb + off);         // 0.88 MB
    off += (size_t)NP * KSH * 2;
    unsigned short* WB   = (unsigned short*)(wsb + off);         // 0.26 MB
    off += (size_t)128 * KP * 2;
    unsigned short* XTa  = (unsigned short*)(wsb + off);         // 8.98 MB alloc
    unsigned short* XT   = XTa + (size_t)XGUARD * CP;            // guarded base
    unsigned short* S    = XTa;   // S overlays XT (dead after pg_shift)

    const bool full = ws_size >= off + (size_t)MFULL * KP * 2;   // 93.0 MB total
    const int cnt = full ? MFULL : MHALF;
    const int nh  = full ? 1 : 2;

    // prep: zero XT + build B2 + WB
    {
        int tot = ZN + B2N + WBN;
        prep_kernel<<<(tot + 255) / 256, 256, 0, stream>>>(pgw, w, XTa, B2, WB);
    }
    // transpose x -> XT (NHWC bf16, 66x66 halo)
    xpose_kernel<<<dim3(Hn, Bn), 256, 0, stream>>>(x, XT);

    // pg conv as shift-GEMM
    pg_shift_kernel<<<dim3(MPAD / 128, NP / 128), 256, 0, stream>>>(
        XT, B2, pgb, pgBF);

    // deformable sampling -> S, then main GEMM -> out
    for (int h = 0; h < nh; ++h) {
        sample_kernel<<<dim3(cnt / 256, Gn), 256, 0, stream>>>(
            x, pgBF, S, h * cnt);
        main_gemm_kernel<<<dim3(cnt / 128, 1), 256, 0, stream>>>(
            S, WB, bias, out, h * cnt);
    }
}

// Round 8
// 181.152 us; speedup vs baseline: 1.2150x; 1.1788x over previous
//
#include <hip/hip_runtime.h>
#include <math.h>

#define Bn 8
#define Cn 112
#define Hn 64
#define Wn 64
#define On 112
#define Gn 14
#define PGC 378          // 3*G*K2
#define HW 4096          // 64*64
#define CKW 1008         // C*K2
#define KP 1024          // padded K for main GEMM (sampled layout)
#define NP 384           // padded N (oc) for pg GEMM
#define KSH 1152         // shift-GEMM K = 9 taps * 128 padded channels
#define CP 128           // padded channel count
#define MFULL 32768
#define XROW 4356        // 66*66 rows per batch in XT
#define MPAD 34944       // 273*128 tile-padded px'' domain
#define XGUARD 67
#define XALLOC_ROWS (XGUARD + MPAD + XGUARD + 2)   // 35080

typedef __attribute__((ext_vector_type(8))) short bf16x8;
typedef __attribute__((ext_vector_type(4))) float f32x4;

__device__ __forceinline__ unsigned short f2bf(float f) {
    union { float f; unsigned int u; } v; v.f = f;
    unsigned int r = v.u + 0x7fffu + ((v.u >> 16) & 1u);
    return (unsigned short)(r >> 16);
}
__device__ __forceinline__ float bf2f(unsigned short u) {
    union { unsigned int u; float f; } v; v.u = ((unsigned int)u) << 16;
    return v.f;
}
__device__ __forceinline__ float bflo(unsigned int u) {
    union { unsigned int u; float f; } v; v.u = u << 16; return v.f;
}
__device__ __forceinline__ float bfhi(unsigned int u) {
    union { unsigned int u; float f; } v; v.u = u & 0xffff0000u; return v.f;
}
__device__ __forceinline__ void gload_lds16(const void* g, void* l) {
    __builtin_amdgcn_global_load_lds(
        (const __attribute__((address_space(1))) unsigned int*)g,
        (__attribute__((address_space(3))) unsigned int*)l, 16, 0, 0);
}

// ---------------------------------------------------------------------------
// prep (merged): zero XT alloc | B2 shift-layout [384][1152] | WB [128][1024]
// ---------------------------------------------------------------------------
#define ZN (XALLOC_ROWS * CP / 8)
#define B2N (NP * KSH)
#define WBN (128 * KP)
__global__ __launch_bounds__(256) void prep_kernel(
    const float* __restrict__ pgw, const float* __restrict__ w,
    unsigned short* __restrict__ XTa, unsigned short* __restrict__ B2,
    unsigned short* __restrict__ WB)
{
    int t = blockIdx.x * 256 + threadIdx.x;
    if (t < ZN) {
        const uint4 z = {0, 0, 0, 0};
        reinterpret_cast<uint4*>(XTa)[t] = z;
        return;
    }
    t -= ZN;
    if (t < B2N) {
        int oc = t / KSH, ckk = t - oc * KSH;
        int k = ckk >> 7, c = ckk & 127;
        float v = (c < Cn && oc < PGC) ? pgw[(size_t)oc * CKW + c * 9 + k] : 0.f;
        B2[t] = f2bf(v);
        return;
    }
    t -= B2N;
    if (t < WBN) {
        int oc = t >> 10, ck = t & 1023;
        float v = 0.f;
        if (oc < On && ck < CKW) {
            int g = ck / 72, r = ck % 72;
            int k = r >> 3, cc = r & 7;
            v = w[(size_t)oc * CKW + (g * 8 + cc) * 9 + k];
        }
        WB[t] = f2bf(v);
    }
}

// ---------------------------------------------------------------------------
// xpose: x NCHW f32 -> XT bf16 rows [(b*66 + y+1)*66 + x+1][128]
// ---------------------------------------------------------------------------
__global__ __launch_bounds__(256) void xpose_kernel(
    const float* __restrict__ x, unsigned short* __restrict__ XT)
{
    __shared__ unsigned short lds[64][136];

    const int tid = threadIdx.x;
    const int y = blockIdx.x, b = blockIdx.y;
    const int xx = tid & 63, cw = tid >> 6;

    const float* xb = x + (size_t)b * Cn * HW + y * 64;
    #pragma unroll
    for (int p = 0; p < 28; ++p) {
        int c = p * 4 + cw;
        lds[xx][c] = f2bf(xb[(size_t)c * HW + xx]);
        if (p < 4) lds[xx][112 + p * 4 + cw] = 0;
    }
    __syncthreads();

    const int rx = tid >> 2, seg = tid & 3;
    size_t row = (size_t)(b * 66 + y + 1) * 66 + rx + 1;
    unsigned short* dst = XT + row * CP + seg * 32;
    const unsigned short* srcr = &lds[rx][seg * 32];
    #pragma unroll
    for (int j = 0; j < 4; ++j)
        *reinterpret_cast<uint4*>(dst + j * 8) =
            *reinterpret_cast<const uint4*>(srcr + j * 8);
}

// ---------------------------------------------------------------------------
// pg shift-GEMM (validated round 7): 128x128 tile, 36 K-steps
// ---------------------------------------------------------------------------
__global__ __launch_bounds__(256) void pg_shift_kernel(
    const unsigned short* __restrict__ XT, const unsigned short* __restrict__ B2,
    const float* __restrict__ pgb, unsigned short* __restrict__ pgBF)
{
    __shared__ __align__(16) unsigned short Asm[128 * 32];
    __shared__ __align__(16) unsigned short Bsm[128 * 32];

    const int tid  = threadIdx.x;
    const int lane = tid & 63;
    const int w    = tid >> 6;
    const int wr   = w >> 1, wc = w & 1;
    const int m0   = blockIdx.x * 128;
    const int n0   = blockIdx.y * 128;
    const int fr   = lane & 15, fq = lane >> 4;

    f32x4 acc[4][4] = {};

    const int ldr = lane >> 2;
    const int ldcA = (lane & 3) * 8;
    const int ldcB = (lane & 3) * 8;

    for (int kt = 0; kt < 36; ++kt) {
        const int k = kt >> 2;
        const int shift = (k / 3 - 1) * 66 + (k % 3 - 1);
        const int c0 = (kt & 3) * 32;
        if (kt) __syncthreads();
        #pragma unroll
        for (int i = 0; i < 2; ++i) {
            int row = w * 32 + i * 16 + ldr;
            gload_lds16(&XT[(size_t)(m0 + row + shift) * CP + c0 + ldcA],
                        &Asm[(w * 32 + i * 16) * 32]);
            gload_lds16(&B2[(size_t)(n0 + row) * KSH + kt * 32 + ldcB],
                        &Bsm[(w * 32 + i * 16) * 32]);
        }
        __syncthreads();

        bf16x8 a[4], b[4];
        #pragma unroll
        for (int mi = 0; mi < 4; ++mi)
            a[mi] = *reinterpret_cast<const bf16x8*>(
                &Asm[(wr * 64 + mi * 16 + fr) * 32 + fq * 8]);
        #pragma unroll
        for (int ni = 0; ni < 4; ++ni)
            b[ni] = *reinterpret_cast<const bf16x8*>(
                &Bsm[(wc * 64 + ni * 16 + fr) * 32 + fq * 8]);
        #pragma unroll
        for (int mi = 0; mi < 4; ++mi)
            #pragma unroll
            for (int ni = 0; ni < 4; ++ni)
                acc[mi][ni] = __builtin_amdgcn_mfma_f32_16x16x32_bf16(
                    a[mi], b[ni], acc[mi][ni], 0, 0, 0);
    }

    #pragma unroll
    for (int ni = 0; ni < 4; ++ni) {
        int oc = n0 + wc * 64 + ni * 16 + fr;
        if (oc >= PGC) continue;
        float bias = pgb[oc];
        #pragma unroll
        for (int mi = 0; mi < 4; ++mi) {
            int pxq = m0 + wr * 64 + mi * 16 + fq * 4;
            #pragma unroll
            for (int r = 0; r < 4; ++r) {
                int pxd = pxq + r;
                if (pxd >= Bn * XROW) continue;
                int bb = pxd / XROW;
                int rem = pxd - bb * XROW;
                int yy = rem / 66 - 1;
                int xx = rem - (yy + 1) * 66 - 1;
                if ((unsigned)yy < 64u && (unsigned)xx < 64u)
                    pgBF[((size_t)(bb * PGC + oc)) * HW + yy * 64 + xx] =
                        f2bf(acc[mi][ni][r] + bias);
            }
        }
    }
}

// ---------------------------------------------------------------------------
// sample: thread = (pixel, (g,k) tap); gathers 4 bf16 corner rows (16B each)
// from NHWC XT; writes 16B into tiled S [px/128][ck/8][px%128][8ck].
// cb == gk because ck_base = g*72 + k*8 = 8*(9g + k) = 8*gk.
// ---------------------------------------------------------------------------
__global__ __launch_bounds__(256) void sample_kernel(
    const unsigned short* __restrict__ XT, const unsigned short* __restrict__ pg,
    unsigned short* __restrict__ S, int px_base)
{
    const int pxl = blockIdx.x * 256 + threadIdx.x;
    const int gk  = blockIdx.y;              // 0..125
    const int g = gk / 9, k = gk - 9 * g;
    const int pxg = px_base + pxl;
    const int b = pxg >> 12, hw = pxg & 4095;
    const int y = hw >> 6, xc = hw & 63;
    const int pblk = pxl >> 7, prem = pxl & 127;

    if (gk == 0) {   // zero K-pad blocks cb = 126, 127
        const uint4 z = {0, 0, 0, 0};
        *reinterpret_cast<uint4*>(
            &S[(((size_t)pblk * 128 + 126) * 128 + prem) * 8]) = z;
        *reinterpret_cast<uint4*>(
            &S[(((size_t)pblk * 128 + 127) * 128 + prem) * 8]) = z;
    }

    const unsigned short* pgb = pg + (size_t)b * PGC * HW + hw;
    float dy = bf2f(pgb[(size_t)(18 * g + 2 * k) * HW]);
    float dx = bf2f(pgb[(size_t)(18 * g + 2 * k + 1) * HW]);
    float mv = bf2f(pgb[(size_t)(252 + 9 * g + k) * HW]);
    float m  = 1.f / (1.f + __expf(-mv));

    const int ky = k / 3, kx = k % 3;
    float yf = (float)(y + ky - 1) + dy;
    float xf = (float)(xc + kx - 1) + dx;
    float y0 = floorf(yf), x0 = floorf(xf);
    float wy1 = yf - y0, wx1 = xf - x0;
    float wy0 = 1.f - wy1, wx0 = 1.f - wx1;
    int iy0 = (int)y0, ix0 = (int)x0;
    bool vy0 = (iy0 >= 0) && (iy0 < Hn);
    bool vy1 = (iy0 >= -1) && (iy0 < Hn - 1);
    bool vx0 = (ix0 >= 0) && (ix0 < Wn);
    bool vx1 = (ix0 >= -1) && (ix0 < Wn - 1);
    int cy0 = min(max(iy0, 0), Hn - 1), cy1 = min(max(iy0 + 1, 0), Hn - 1);
    int cx0 = min(max(ix0, 0), Wn - 1), cx1 = min(max(ix0 + 1, 0), Wn - 1);
    float w00 = (vy0 && vx0) ? wy0 * wx0 * m : 0.f;
    float w01 = (vy0 && vx1) ? wy0 * wx1 * m : 0.f;
    float w10 = (vy1 && vx0) ? wy1 * wx0 * m : 0.f;
    float w11 = (vy1 && vx1) ? wy1 * wx1 * m : 0.f;

    // 4 corner rows, 8 channels each (16 B), all in flight
    const unsigned short* xtb = XT + (size_t)(b * 66) * 66 * CP + g * 8;
    const int r00 = (cy0 + 1) * 66 + cx0 + 1, r01 = (cy0 + 1) * 66 + cx1 + 1;
    const int r10 = (cy1 + 1) * 66 + cx0 + 1, r11 = (cy1 + 1) * 66 + cx1 + 1;
    uint4 q00 = *reinterpret_cast<const uint4*>(xtb + (size_t)r00 * CP);
    uint4 q01 = *reinterpret_cast<const uint4*>(xtb + (size_t)r01 * CP);
    uint4 q10 = *reinterpret_cast<const uint4*>(xtb + (size_t)r10 * CP);
    uint4 q11 = *reinterpret_cast<const uint4*>(xtb + (size_t)r11 * CP);

    unsigned int c00[4] = {q00.x, q00.y, q00.z, q00.w};
    unsigned int c01[4] = {q01.x, q01.y, q01.z, q01.w};
    unsigned int c10[4] = {q10.x, q10.y, q10.z, q10.w};
    unsigned int c11[4] = {q11.x, q11.y, q11.z, q11.w};

    unsigned int pk[4];
    #pragma unroll
    for (int j = 0; j < 4; ++j) {
        float lo = bflo(c00[j]) * w00 + bflo(c01[j]) * w01 +
                   bflo(c10[j]) * w10 + bflo(c11[j]) * w11;
        float hi = bfhi(c00[j]) * w00 + bfhi(c01[j]) * w01 +
                   bfhi(c10[j]) * w10 + bfhi(c11[j]) * w11;
        pk[j] = (unsigned int)f2bf(lo) | ((unsigned int)f2bf(hi) << 16);
    }
    *reinterpret_cast<uint4*>(
        &S[(((size_t)pblk * 128 + gk) * 128 + prem) * 8]) =
        *reinterpret_cast<const uint4*>(pk);
}

// ---------------------------------------------------------------------------
// main GEMM: out[b][oc][hw] = S_tiled[px][ck] * WB[oc][ck] + bias[oc]
// ---------------------------------------------------------------------------
__global__ __launch_bounds__(256) void main_gemm_kernel(
    const unsigned short* __restrict__ S, const unsigned short* __restrict__ WB,
    const float* __restrict__ bias, float* __restrict__ out, int px_base)
{
    __shared__ __align__(16) unsigned short Asm[128 * 32];
    __shared__ __align__(16) unsigned short Bsm[128 * 32];

    const int tid  = threadIdx.x;
    const int lane = tid & 63;
    const int w    = tid >> 6;
    const int wr   = w >> 1, wc = w & 1;
    const int m0   = blockIdx.x * 128;
    const int fr   = lane & 15, fq = lane >> 4;

    f32x4 acc[4][4] = {};

    const int ldr = lane >> 2;
    const int lq  = lane & 3;
    const int ldc = lq * 8;

    for (int kt = 0; kt < 32; ++kt) {
        if (kt) __syncthreads();
        #pragma unroll
        for (int i = 0; i < 2; ++i) {
            int row = w * 32 + i * 16 + ldr;
            int cb  = kt * 4 + lq;
            gload_lds16(&S[(((size_t)blockIdx.x * 128 + cb) * 128 + row) * 8],
                        &Asm[(w * 32 + i * 16) * 32]);
            gload_lds16(&WB[(size_t)row * KP + kt * 32 + ldc],
                        &Bsm[(w * 32 + i * 16) * 32]);
        }
        __syncthreads();

        bf16x8 a[4], b[4];
        #pragma unroll
        for (int mi = 0; mi < 4; ++mi)
            a[mi] = *reinterpret_cast<const bf16x8*>(
                &Asm[(wr * 64 + mi * 16 + fr) * 32 + fq * 8]);
        #pragma unroll
        for (int ni = 0; ni < 4; ++ni)
            b[ni] = *reinterpret_cast<const bf16x8*>(
                &Bsm[(wc * 64 + ni * 16 + fr) * 32 + fq * 8]);
        #pragma unroll
        for (int mi = 0; mi < 4; ++mi)
            #pragma unroll
            for (int ni = 0; ni < 4; ++ni)
                acc[mi][ni] = __builtin_amdgcn_mfma_f32_16x16x32_bf16(
                    a[mi], b[ni], acc[mi][ni], 0, 0, 0);
    }

    #pragma unroll
    for (int ni = 0; ni < 4; ++ni) {
        int oc = wc * 64 + ni * 16 + fr;
        if (oc >= On) continue;
        float bv = bias[oc];
        #pragma unroll
        for (int mi = 0; mi < 4; ++mi) {
            int pxl = m0 + wr * 64 + mi * 16 + fq * 4;
            int pxg = px_base + pxl;
            int b = pxg >> 12, hw = pxg & 4095;
            float4 o;
            o.x = acc[mi][ni][0] + bv;
            o.y = acc[mi][ni][1] + bv;
            o.z = acc[mi][ni][2] + bv;
            o.w = acc[mi][ni][3] + bv;
            *reinterpret_cast<float4*>(
                &out[((size_t)(b * On + oc)) * HW + hw]) = o;
        }
    }
}

// ---------------------------------------------------------------------------
extern "C" void kernel_launch(void* const* d_in, const int* in_sizes, int n_in,
                              void* d_out, int out_size, void* d_ws, size_t ws_size,
                              hipStream_t stream) {
    const float* x    = (const float*)d_in[0];
    const float* pgw  = (const float*)d_in[1];
    const float* pgb  = (const float*)d_in[2];
    const float* w    = (const float*)d_in[3];
    const float* bias = (const float*)d_in[4];
    float* out = (float*)d_out;

    char* wsb = (char*)d_ws;
    unsigned short* pgBF = (unsigned short*)wsb;                 // 24.77 MB
    size_t off = (size_t)PGC * Bn * HW * 2;
    unsigned short* B2   = (unsigned short*)(wsb + off);         // 0.88 MB
    off += (size_t)NP * KSH * 2;
    unsigned short* WB   = (unsigned short*)(wsb + off);         // 0.26 MB
    off += (size_t)128 * KP * 2;
    unsigned short* XTa  = (unsigned short*)(wsb + off);         // 8.98 MB
    unsigned short* XT   = XTa + (size_t)XGUARD * CP;
    off += (size_t)XALLOC_ROWS * CP * 2;
    unsigned short* S    = (unsigned short*)(wsb + off);         // sampled (tiled)

    const size_t sfull = (size_t)MFULL * KP * 2;                 // 67.1 MB
    int nh;
    if (ws_size >= off + sfull)          nh = 1;   // 102.0 MB total
    else if (ws_size >= off + sfull / 2) nh = 2;   //  68.4 MB
    else                                 nh = 4;   //  51.7 MB
    const int cnt = MFULL / nh;

    // prep: zero XT + build B2 + WB
    {
        int tot = ZN + B2N + WBN;
        prep_kernel<<<(tot + 255) / 256, 256, 0, stream>>>(pgw, w, XTa, B2, WB);
    }
    // transpose x -> XT (NHWC bf16, 66x66 halo)
    xpose_kernel<<<dim3(Hn, Bn), 256, 0, stream>>>(x, XT);

    // pg conv as shift-GEMM
    pg_shift_kernel<<<dim3(MPAD / 128, NP / 128), 256, 0, stream>>>(
        XT, B2, pgb, pgBF);

    // deformable sampling (NHWC corner loads) -> tiled S, then main GEMM
    for (int h = 0; h < nh; ++h) {
        sample_kernel<<<dim3(cnt / 256, 126), 256, 0, stream>>>(
            XT, pgBF, S, h * cnt);
        main_gemm_kernel<<<dim3(cnt / 128, 1), 256, 0, stream>>>(
            S, WB, bias, out, h * cnt);
    }
}